// Round 1
// baseline (596.383 us; speedup 1.0000x reference)
//
#include <hip/hip_runtime.h>
#include <stdint.h>

#define NUM_NODES 1000000
#define H_DIM 64
#define OUT_DIM 32
#define NUM_RELS 64
#define NUM_BASES 4
#define N_SRC0 400000
#define N_DST1 100000
#define N_DST2 20000
#define E1 600000
#define E2 300000

typedef __attribute__((ext_vector_type(8))) short bf16x8;
typedef __attribute__((ext_vector_type(4))) float floatx4;

__device__ __forceinline__ unsigned short f2bf(float f){
  union{float f; unsigned u;} v; v.f=f;
  unsigned u=v.u;
  unsigned r=(u + 0x7FFFu + ((u>>16)&1u))>>16;
  return (unsigned short)r;
}
__device__ __forceinline__ float bf2f(unsigned short h){
  union{unsigned u; float f;} v; v.u=((unsigned)h)<<16; return v.f;
}

// ---- gather x = bf16(emb[input_nodes]) ----
__global__ void k_gather_x(const int* __restrict__ input_nodes,
                           const float* __restrict__ emb,
                           ushort* __restrict__ x_bf){
  int t = blockIdx.x*blockDim.x + threadIdx.x;
  if (t >= N_SRC0*16) return;
  int row = t >> 4, seg = t & 15;
  int idx = input_nodes[row];
  float4 v = ((const float4*)emb)[(size_t)idx*16 + seg];
  ushort4 o; o.x=f2bf(v.x); o.y=f2bf(v.y); o.z=f2bf(v.z); o.w=f2bf(v.w);
  ((ushort4*)x_bf)[(size_t)row*16 + seg] = o;
}

// ---- B fragment tables (fragment-ordered, bf16): B[n=k*4+b][o] = V[b][k][o] ----
__global__ void k_btab(const float* __restrict__ V1, const float* __restrict__ V2,
                       ushort* __restrict__ Btab1, ushort* __restrict__ Btab2){
  int t = blockIdx.x*blockDim.x + threadIdx.x;
  if (t < 16384){
    int j = t & 7, lane = (t>>3)&63, kk = (t>>9)&7, nt = t>>12;     // nt<4
    int kdim = kk*32 + (lane>>4)*8 + j;
    int o = nt*16 + (lane&15);
    int k = kdim>>2, b = kdim&3;
    Btab1[t] = f2bf(V1[(b*64 + k)*64 + o]);
  } else if (t < 24576){
    int u = t - 16384;
    int j = u & 7, lane = (u>>3)&63, kk = (u>>9)&7, nt = u>>12;     // nt<2
    int kdim = kk*32 + (lane>>4)*8 + j;
    int o = nt*16 + (lane&15);
    int k = kdim>>2, b = kdim&3;
    Btab2[u] = f2bf(V2[(b*64 + k)*32 + o]);
  }
}

// ---- CSR build ----
__global__ void k_hist(const int* __restrict__ dst, int* __restrict__ deg, int n){
  int t = blockIdx.x*blockDim.x + threadIdx.x;
  if (t < n) atomicAdd(&deg[dst[t]], 1);
}

__global__ void k_scan_sum(const int* __restrict__ deg, int* __restrict__ bsum, int n){
  __shared__ int lds[256];
  int tid = threadIdx.x;
  int base = blockIdx.x*1024 + tid*4;
  int s = 0;
  #pragma unroll
  for (int j=0;j<4;j++){ int i = base+j; if (i<n) s += deg[i]; }
  lds[tid] = s; __syncthreads();
  for (int off=128; off>0; off>>=1){ if (tid<off) lds[tid] += lds[tid+off]; __syncthreads(); }
  if (tid==0) bsum[blockIdx.x] = lds[0];
}

__global__ void k_scan_bsum(const int* __restrict__ bsum, int* __restrict__ boff, int nb){
  __shared__ int lds[256];
  int tid = threadIdx.x;
  int v = (tid<nb) ? bsum[tid] : 0;
  lds[tid] = v; __syncthreads();
  for (int off=1; off<256; off<<=1){
    int t = (tid>=off) ? lds[tid-off] : 0; __syncthreads();
    lds[tid] += t; __syncthreads();
  }
  if (tid<nb) boff[tid] = lds[tid] - v;   // exclusive
}

__global__ void k_scan_final(const int* __restrict__ deg, const int* __restrict__ boff,
                             int* __restrict__ offs, int* __restrict__ cursor, int n){
  __shared__ int lds[256];
  int tid = threadIdx.x;
  int base = blockIdx.x*1024 + tid*4;
  int a[4]; int s = 0;
  #pragma unroll
  for (int j=0;j<4;j++){ int i = base+j; a[j] = (i<n)?deg[i]:0; s += a[j]; }
  lds[tid] = s; __syncthreads();
  for (int off=1; off<256; off<<=1){
    int t = (tid>=off) ? lds[tid-off] : 0; __syncthreads();
    lds[tid] += t; __syncthreads();
  }
  int run = boff[blockIdx.x] + (lds[tid] - s);   // global exclusive prefix
  #pragma unroll
  for (int j=0;j<4;j++){
    int i = base+j;
    if (i<n){
      offs[i] = run; cursor[i] = run;
      run += a[j];
      if (i == n-1) offs[n] = run;
    }
  }
}

__global__ void k_scatter(const int* __restrict__ src, const int* __restrict__ dst,
                          const int* __restrict__ ety, const float* __restrict__ nrm,
                          const float* __restrict__ comp,
                          int* __restrict__ cursor, int* __restrict__ ssrc,
                          float4* __restrict__ sc, int n){
  int t = blockIdx.x*blockDim.x + threadIdx.x;
  if (t >= n) return;
  int d = dst[t];
  int p = atomicAdd(&cursor[d], 1);
  ssrc[p] = src[t];
  float nv = nrm[t];
  float4 cp = ((const float4*)comp)[ety[t]];
  float4 c; c.x = cp.x*nv; c.y = cp.y*nv; c.z = cp.z*nv; c.w = cp.w*nv;
  sc[p] = c;
}

// ---- edge aggregation: z[d][k*4+b] = sum_{e->d} c_eb * x[src_e][k]  (wave per dst) ----
__global__ void k_agg(const ushort* __restrict__ xin, const int* __restrict__ offs,
                      const int* __restrict__ ssrc, const float4* __restrict__ sc,
                      ushort* __restrict__ z, int ndst){
  int w = (blockIdx.x*blockDim.x + threadIdx.x) >> 6;
  int lane = threadIdx.x & 63;
  if (w >= ndst) return;
  int e0 = offs[w], e1 = offs[w+1];
  float a0=0.f, a1=0.f, a2=0.f, a3=0.f;
  for (int e=e0; e<e1; ++e){
    int s = ssrc[e];
    float4 c = sc[e];
    float xv = bf2f(xin[(size_t)s*64 + lane]);
    a0 = fmaf(c.x, xv, a0);
    a1 = fmaf(c.y, xv, a1);
    a2 = fmaf(c.z, xv, a2);
    a3 = fmaf(c.w, xv, a3);
  }
  ushort4 o; o.x=f2bf(a0); o.y=f2bf(a1); o.z=f2bf(a2); o.w=f2bf(a3);
  ((ushort4*)z)[(size_t)w*64 + lane] = o;
}

// ---- GEMM1: h = relu(z1 @ B1 + b1), M=100000 K=256 N=64, bf16 MFMA ----
__global__ void k_gemm1(const ushort* __restrict__ z1, const ushort* __restrict__ Btab1,
                        const float* __restrict__ bias, ushort* __restrict__ h_bf){
  int wid = (blockIdx.x*blockDim.x + threadIdx.x) >> 6;
  int lane = threadIdx.x & 63;
  int rowBase = wid*16;
  if (rowBase >= N_DST1) return;
  int quad = lane>>4, l15 = lane&15;
  const ushort* arow = z1 + (size_t)(rowBase + l15)*256;
  bf16x8 a[8];
  #pragma unroll
  for (int kk=0; kk<8; kk++)
    a[kk] = *((const bf16x8*)(arow + kk*32 + quad*8));
  #pragma unroll
  for (int nt=0; nt<4; nt++){
    floatx4 acc = {0.f,0.f,0.f,0.f};
    #pragma unroll
    for (int kk=0; kk<8; kk++){
      bf16x8 b = *((const bf16x8*)(Btab1 + ((nt*8 + kk)*64 + lane)*8));
      acc = __builtin_amdgcn_mfma_f32_16x16x32_bf16(a[kk], b, acc, 0, 0, 0);
    }
    int col = nt*16 + l15;
    float bv = bias[col];
    #pragma unroll
    for (int r=0; r<4; r++){
      int row = rowBase + quad*4 + r;
      float v = acc[r] + bv;
      v = fmaxf(v, 0.f);
      h_bf[(size_t)row*64 + col] = f2bf(v);
    }
  }
}

// ---- GEMM2: out = z2 @ B2 + b2, M=20000 K=256 N=32, fp32 out ----
__global__ void k_gemm2(const ushort* __restrict__ z2, const ushort* __restrict__ Btab2,
                        const float* __restrict__ bias, float* __restrict__ out){
  int wid = (blockIdx.x*blockDim.x + threadIdx.x) >> 6;
  int lane = threadIdx.x & 63;
  int rowBase = wid*16;
  if (rowBase >= N_DST2) return;
  int quad = lane>>4, l15 = lane&15;
  const ushort* arow = z2 + (size_t)(rowBase + l15)*256;
  bf16x8 a[8];
  #pragma unroll
  for (int kk=0; kk<8; kk++)
    a[kk] = *((const bf16x8*)(arow + kk*32 + quad*8));
  #pragma unroll
  for (int nt=0; nt<2; nt++){
    floatx4 acc = {0.f,0.f,0.f,0.f};
    #pragma unroll
    for (int kk=0; kk<8; kk++){
      bf16x8 b = *((const bf16x8*)(Btab2 + ((nt*8 + kk)*64 + lane)*8));
      acc = __builtin_amdgcn_mfma_f32_16x16x32_bf16(a[kk], b, acc, 0, 0, 0);
    }
    int col = nt*16 + l15;
    float bv = bias[col];
    #pragma unroll
    for (int r=0; r<4; r++){
      int row = rowBase + quad*4 + r;
      out[(size_t)row*32 + col] = acc[r] + bv;
    }
  }
}

extern "C" void kernel_launch(void* const* d_in, const int* in_sizes, int n_in,
                              void* d_out, int out_size, void* d_ws, size_t ws_size,
                              hipStream_t stream){
  const int*   input_nodes = (const int*)  d_in[0];
  const int*   src1  = (const int*)  d_in[1];
  const int*   dst1  = (const int*)  d_in[2];
  const int*   ety1  = (const int*)  d_in[3];
  const float* norm1 = (const float*)d_in[4];
  const int*   src2  = (const int*)  d_in[5];
  const int*   dst2  = (const int*)  d_in[6];
  const int*   ety2  = (const int*)  d_in[7];
  const float* norm2 = (const float*)d_in[8];
  const float* emb   = (const float*)d_in[9];
  const float* V1    = (const float*)d_in[10];
  const float* comp1 = (const float*)d_in[11];
  const float* b1    = (const float*)d_in[12];
  const float* V2    = (const float*)d_in[13];
  const float* comp2 = (const float*)d_in[14];
  const float* b2    = (const float*)d_in[15];
  float* out = (float*)d_out;

  char* p = (char*)d_ws;
  auto alloc = [&](size_t bytes)->char*{
    char* r = p; p += (bytes + 255) & ~(size_t)255; return r;
  };
  ushort* x_bf  = (ushort*)alloc((size_t)N_SRC0*64*2);     // 51.2 MB
  ushort* z1    = (ushort*)alloc((size_t)N_DST1*256*2);    // 51.2 MB
  ushort* h_bf  = (ushort*)alloc((size_t)N_DST1*64*2);     // 12.8 MB
  ushort* z2    = (ushort*)alloc((size_t)N_DST2*256*2);    // 10.2 MB
  ushort* Btab1 = (ushort*)alloc(16384*2);
  ushort* Btab2 = (ushort*)alloc(8192*2);
  int* deg1 = (int*)alloc((size_t)N_DST1*4);
  int* cur1 = (int*)alloc((size_t)N_DST1*4);
  int* off1 = (int*)alloc((size_t)(N_DST1+1)*4);
  int* bs1  = (int*)alloc(256*4);
  int* bo1  = (int*)alloc(256*4);
  int* ssrc1 = (int*)alloc((size_t)E1*4);
  float4* sc1 = (float4*)alloc((size_t)E1*16);
  int* deg2 = (int*)alloc((size_t)N_DST2*4);
  int* cur2 = (int*)alloc((size_t)N_DST2*4);
  int* off2 = (int*)alloc((size_t)(N_DST2+1)*4);
  int* bs2  = (int*)alloc(256*4);
  int* bo2  = (int*)alloc(256*4);
  int* ssrc2 = (int*)alloc((size_t)E2*4);
  float4* sc2 = (float4*)alloc((size_t)E2*16);

  (void)hipMemsetAsync(deg1, 0, (size_t)N_DST1*4, stream);
  (void)hipMemsetAsync(deg2, 0, (size_t)N_DST2*4, stream);

  // x gather + B tables
  k_gather_x<<<(N_SRC0*16 + 255)/256, 256, 0, stream>>>(input_nodes, emb, x_bf);
  k_btab<<<96, 256, 0, stream>>>(V1, V2, Btab1, Btab2);

  // CSR graph 1
  k_hist<<<(E1+255)/256, 256, 0, stream>>>(dst1, deg1, E1);
  int nb1 = (N_DST1 + 1023)/1024;   // 98
  k_scan_sum<<<nb1, 256, 0, stream>>>(deg1, bs1, N_DST1);
  k_scan_bsum<<<1, 256, 0, stream>>>(bs1, bo1, nb1);
  k_scan_final<<<nb1, 256, 0, stream>>>(deg1, bo1, off1, cur1, N_DST1);
  k_scatter<<<(E1+255)/256, 256, 0, stream>>>(src1, dst1, ety1, norm1, comp1,
                                              cur1, ssrc1, sc1, E1);
  // layer 1
  k_agg<<<(N_DST1*64)/256, 256, 0, stream>>>(x_bf, off1, ssrc1, sc1, z1, N_DST1);
  k_gemm1<<<(N_DST1/16 + 3)/4, 256, 0, stream>>>(z1, Btab1, b1, h_bf);

  // CSR graph 2
  k_hist<<<(E2+255)/256, 256, 0, stream>>>(dst2, deg2, E2);
  int nb2 = (N_DST2 + 1023)/1024;   // 20
  k_scan_sum<<<nb2, 256, 0, stream>>>(deg2, bs2, N_DST2);
  k_scan_bsum<<<1, 256, 0, stream>>>(bs2, bo2, nb2);
  k_scan_final<<<nb2, 256, 0, stream>>>(deg2, bo2, off2, cur2, N_DST2);
  k_scatter<<<(E2+255)/256, 256, 0, stream>>>(src2, dst2, ety2, norm2, comp2,
                                              cur2, ssrc2, sc2, E2);
  // layer 2
  k_agg<<<(N_DST2*64)/256, 256, 0, stream>>>(h_bf, off2, ssrc2, sc2, z2, N_DST2);
  k_gemm2<<<(N_DST2/16 + 3)/4, 256, 0, stream>>>(z2, Btab2, b2, out);

  (void)in_sizes; (void)n_in; (void)out_size; (void)ws_size;
}

// Round 2
// 541.633 us; speedup vs baseline: 1.1011x; 1.1011x over previous
//
#include <hip/hip_runtime.h>
#include <stdint.h>

#define NUM_NODES 1000000
#define H_DIM 64
#define OUT_DIM 32
#define NUM_RELS 64
#define NUM_BASES 4
#define N_SRC0 400000
#define N_DST1 100000
#define N_DST2 20000
#define E1 600000
#define E2 300000
#define NDST_TOT (N_DST1 + N_DST2)
#define E_TOT (E1 + E2)

typedef __attribute__((ext_vector_type(8))) short bf16x8;
typedef __attribute__((ext_vector_type(4))) float floatx4;

__device__ __forceinline__ unsigned short f2bf(float f){
  union{float f; unsigned u;} v; v.f=f;
  unsigned u=v.u;
  unsigned r=(u + 0x7FFFu + ((u>>16)&1u))>>16;
  return (unsigned short)r;
}
__device__ __forceinline__ float bf2f(unsigned short h){
  union{unsigned u; float f;} v; v.u=((unsigned)h)<<16; return v.f;
}

// ---- init: zero deg[120000] + build B fragment tables ----
__global__ void k_init(const float* __restrict__ V1, const float* __restrict__ V2,
                       ushort* __restrict__ Btab1, ushort* __restrict__ Btab2,
                       int* __restrict__ deg){
  int t = blockIdx.x*blockDim.x + threadIdx.x;
  if (t < NDST_TOT) deg[t] = 0;
  if (t < 16384){
    int j = t & 7, lane = (t>>3)&63, kk = (t>>9)&7, nt = t>>12;     // nt<4
    int kdim = kk*32 + (lane>>4)*8 + j;
    int o = nt*16 + (lane&15);
    int k = kdim>>2, b = kdim&3;
    Btab1[t] = f2bf(V1[(b*64 + k)*64 + o]);
  } else if (t < 24576){
    int u = t - 16384;
    int j = u & 7, lane = (u>>3)&63, kk = (u>>9)&7, nt = u>>12;     // nt<2
    int kdim = kk*32 + (lane>>4)*8 + j;
    int o = nt*16 + (lane&15);
    int k = kdim>>2, b = kdim&3;
    Btab2[u] = f2bf(V2[(b*64 + k)*32 + o]);
  }
}

// ---- gather x = bf16(emb[input_nodes]) ----
__global__ void k_gather_x(const int* __restrict__ input_nodes,
                           const float* __restrict__ emb,
                           ushort* __restrict__ x_bf){
  int t = blockIdx.x*blockDim.x + threadIdx.x;
  if (t >= N_SRC0*16) return;
  int row = t >> 4, seg = t & 15;
  int idx = input_nodes[row];
  float4 v = ((const float4*)emb)[(size_t)idx*16 + seg];
  ushort4 o; o.x=f2bf(v.x); o.y=f2bf(v.y); o.z=f2bf(v.z); o.w=f2bf(v.w);
  ((ushort4*)x_bf)[(size_t)row*16 + seg] = o;
}

// ---- histogram over both graphs' dst (graph2 offset by N_DST1) ----
__global__ void k_hist(const int* __restrict__ dst1, const int* __restrict__ dst2,
                       int* __restrict__ deg){
  int t = blockIdx.x*blockDim.x + threadIdx.x;
  if (t < E1) atomicAdd(&deg[dst1[t]], 1);
  else if (t < E_TOT) atomicAdd(&deg[N_DST1 + dst2[t - E1]], 1);
}

// ---- 3-kernel exclusive scan over deg[NDST_TOT] ----
__global__ void k_scan_sum(const int* __restrict__ deg, int* __restrict__ bsum, int n){
  __shared__ int lds[256];
  int tid = threadIdx.x;
  int base = blockIdx.x*1024 + tid*4;
  int s = 0;
  #pragma unroll
  for (int j=0;j<4;j++){ int i = base+j; if (i<n) s += deg[i]; }
  lds[tid] = s; __syncthreads();
  for (int off=128; off>0; off>>=1){ if (tid<off) lds[tid] += lds[tid+off]; __syncthreads(); }
  if (tid==0) bsum[blockIdx.x] = lds[0];
}

__global__ void k_scan_bsum(const int* __restrict__ bsum, int* __restrict__ boff, int nb){
  __shared__ int lds[256];
  int tid = threadIdx.x;
  int v = (tid<nb) ? bsum[tid] : 0;
  lds[tid] = v; __syncthreads();
  for (int off=1; off<256; off<<=1){
    int t = (tid>=off) ? lds[tid-off] : 0; __syncthreads();
    lds[tid] += t; __syncthreads();
  }
  if (tid<nb) boff[tid] = lds[tid] - v;   // exclusive
}

__global__ void k_scan_final(const int* __restrict__ deg, const int* __restrict__ boff,
                             int* __restrict__ offs, int* __restrict__ cursor, int n){
  __shared__ int lds[256];
  int tid = threadIdx.x;
  int base = blockIdx.x*1024 + tid*4;
  int a[4]; int s = 0;
  #pragma unroll
  for (int j=0;j<4;j++){ int i = base+j; a[j] = (i<n)?deg[i]:0; s += a[j]; }
  lds[tid] = s; __syncthreads();
  for (int off=1; off<256; off<<=1){
    int t = (tid>=off) ? lds[tid-off] : 0; __syncthreads();
    lds[tid] += t; __syncthreads();
  }
  int run = boff[blockIdx.x] + (lds[tid] - s);   // global exclusive prefix
  #pragma unroll
  for (int j=0;j<4;j++){
    int i = base+j;
    if (i<n){
      offs[i] = run; cursor[i] = run;
      run += a[j];
      if (i == n-1) offs[n] = run;
    }
  }
}

// ---- scatter both graphs into dst-sorted edge arrays ----
__global__ void k_scatter(const int* __restrict__ src1, const int* __restrict__ dst1,
                          const int* __restrict__ ety1, const float* __restrict__ nrm1,
                          const float* __restrict__ comp1,
                          const int* __restrict__ src2, const int* __restrict__ dst2,
                          const int* __restrict__ ety2, const float* __restrict__ nrm2,
                          const float* __restrict__ comp2,
                          int* __restrict__ cursor, int* __restrict__ ssrc,
                          float4* __restrict__ sc){
  int t = blockIdx.x*blockDim.x + threadIdx.x;
  int d, s, et; float nv; const float* comp;
  if (t < E1){
    d = dst1[t]; s = src1[t]; et = ety1[t]; nv = nrm1[t]; comp = comp1;
  } else if (t < E_TOT){
    int e = t - E1;
    d = N_DST1 + dst2[e]; s = src2[e]; et = ety2[e]; nv = nrm2[e]; comp = comp2;
  } else return;
  int p = atomicAdd(&cursor[d], 1);
  ssrc[p] = s;
  float4 cp = ((const float4*)comp)[et];
  float4 c; c.x = cp.x*nv; c.y = cp.y*nv; c.z = cp.z*nv; c.w = cp.w*nv;
  sc[p] = c;
}

// ---- fused aggregate + GEMM per layer ----
// Block = 256 threads = 4 waves, handles 16 dst rows.
// Wave w aggregates rows w*4..w*4+3 (z[row][k*4+b] in regs), stages 16x256 bf16
// tile in padded LDS, then wave w computes MFMA n-tile w (16 cols).
__device__ __forceinline__ void agg_rows(const ushort* __restrict__ xin,
                                         const int* __restrict__ offs,
                                         const int* __restrict__ ssrc,
                                         const float4* __restrict__ sc,
                                         int mbase, int w, int lane,
                                         ushort zt[16][264]){
  for (int j = 0; j < 4; j++){
    int row = w*4 + j;
    int d = mbase + row;
    int e0 = offs[d], e1 = offs[d+1];
    float a0=0.f, a1=0.f, a2=0.f, a3=0.f;
    for (int base = e0; base < e1; base += 64){
      int m = e1 - base; if (m > 64) m = 64;
      int se = 0; float4 ce = {0.f,0.f,0.f,0.f};
      if (lane < m){ se = ssrc[base + lane]; ce = sc[base + lane]; }
      for (int i = 0; i < m; i++){
        int s = __shfl(se, i);
        float cx = __shfl(ce.x, i), cy = __shfl(ce.y, i);
        float cz = __shfl(ce.z, i), cw = __shfl(ce.w, i);
        float xv = bf2f(xin[(size_t)s*64 + lane]);
        a0 = fmaf(cx, xv, a0); a1 = fmaf(cy, xv, a1);
        a2 = fmaf(cz, xv, a2); a3 = fmaf(cw, xv, a3);
      }
    }
    ushort4 o; o.x=f2bf(a0); o.y=f2bf(a1); o.z=f2bf(a2); o.w=f2bf(a3);
    *(ushort4*)&zt[row][lane*4] = o;
  }
}

__global__ __launch_bounds__(256) void k_agg_gemm1(
    const ushort* __restrict__ xin, const int* __restrict__ offs,
    const int* __restrict__ ssrc, const float4* __restrict__ sc,
    const ushort* __restrict__ Btab, const float* __restrict__ bias,
    ushort* __restrict__ h_bf){
  __shared__ ushort zt[16][264];
  int lane = threadIdx.x & 63;
  int w = threadIdx.x >> 6;
  int mbase = blockIdx.x * 16;
  agg_rows(xin, offs, ssrc, sc, mbase, w, lane, zt);
  __syncthreads();
  int quad = lane>>4, l15 = lane&15;
  bf16x8 a[8];
  #pragma unroll
  for (int kk=0; kk<8; kk++)
    a[kk] = *(const bf16x8*)&zt[l15][kk*32 + quad*8];
  floatx4 acc = {0.f,0.f,0.f,0.f};
  #pragma unroll
  for (int kk=0; kk<8; kk++){
    bf16x8 b = *((const bf16x8*)(Btab + ((w*8 + kk)*64 + lane)*8));
    acc = __builtin_amdgcn_mfma_f32_16x16x32_bf16(a[kk], b, acc, 0, 0, 0);
  }
  int col = w*16 + l15;
  float bv = bias[col];
  #pragma unroll
  for (int r=0; r<4; r++){
    int row = mbase + quad*4 + r;
    float v = fmaxf(acc[r] + bv, 0.f);
    h_bf[(size_t)row*64 + col] = f2bf(v);
  }
}

__global__ __launch_bounds__(256) void k_agg_gemm2(
    const ushort* __restrict__ xin, const int* __restrict__ offs,
    const int* __restrict__ ssrc, const float4* __restrict__ sc,
    const ushort* __restrict__ Btab, const float* __restrict__ bias,
    float* __restrict__ out){
  __shared__ ushort zt[16][264];
  int lane = threadIdx.x & 63;
  int w = threadIdx.x >> 6;
  int mbase = blockIdx.x * 16;
  agg_rows(xin, offs, ssrc, sc, mbase, w, lane, zt);
  __syncthreads();
  if (w >= 2) return;                      // N=32 -> 2 n-tiles
  int quad = lane>>4, l15 = lane&15;
  bf16x8 a[8];
  #pragma unroll
  for (int kk=0; kk<8; kk++)
    a[kk] = *(const bf16x8*)&zt[l15][kk*32 + quad*8];
  floatx4 acc = {0.f,0.f,0.f,0.f};
  #pragma unroll
  for (int kk=0; kk<8; kk++){
    bf16x8 b = *((const bf16x8*)(Btab + ((w*8 + kk)*64 + lane)*8));
    acc = __builtin_amdgcn_mfma_f32_16x16x32_bf16(a[kk], b, acc, 0, 0, 0);
  }
  int col = w*16 + l15;
  float bv = bias[col];
  #pragma unroll
  for (int r=0; r<4; r++){
    int row = mbase + quad*4 + r;
    out[(size_t)row*32 + col] = acc[r] + bv;
  }
}

extern "C" void kernel_launch(void* const* d_in, const int* in_sizes, int n_in,
                              void* d_out, int out_size, void* d_ws, size_t ws_size,
                              hipStream_t stream){
  const int*   input_nodes = (const int*)  d_in[0];
  const int*   src1  = (const int*)  d_in[1];
  const int*   dst1  = (const int*)  d_in[2];
  const int*   ety1  = (const int*)  d_in[3];
  const float* norm1 = (const float*)d_in[4];
  const int*   src2  = (const int*)  d_in[5];
  const int*   dst2  = (const int*)  d_in[6];
  const int*   ety2  = (const int*)  d_in[7];
  const float* norm2 = (const float*)d_in[8];
  const float* emb   = (const float*)d_in[9];
  const float* V1    = (const float*)d_in[10];
  const float* comp1 = (const float*)d_in[11];
  const float* b1    = (const float*)d_in[12];
  const float* V2    = (const float*)d_in[13];
  const float* comp2 = (const float*)d_in[14];
  const float* b2    = (const float*)d_in[15];
  float* out = (float*)d_out;

  char* p = (char*)d_ws;
  auto alloc = [&](size_t bytes)->char*{
    char* r = p; p += (bytes + 255) & ~(size_t)255; return r;
  };
  ushort* x_bf  = (ushort*)alloc((size_t)N_SRC0*64*2);     // 51.2 MB
  ushort* h_bf  = (ushort*)alloc((size_t)N_DST1*64*2);     // 12.8 MB
  ushort* Btab1 = (ushort*)alloc(16384*2);
  ushort* Btab2 = (ushort*)alloc(8192*2);
  int* deg  = (int*)alloc((size_t)NDST_TOT*4);
  int* cur  = (int*)alloc((size_t)NDST_TOT*4);
  int* offs = (int*)alloc((size_t)(NDST_TOT+1)*4);
  int* bs   = (int*)alloc(256*4);
  int* bo   = (int*)alloc(256*4);
  int* ssrc = (int*)alloc((size_t)E_TOT*4);
  float4* sc = (float4*)alloc((size_t)E_TOT*16);

  // 1. init (deg zero + B tables)
  k_init<<<(NDST_TOT + 255)/256, 256, 0, stream>>>(V1, V2, Btab1, Btab2, deg);
  // 2. gather x
  k_gather_x<<<(N_SRC0*16 + 255)/256, 256, 0, stream>>>(input_nodes, emb, x_bf);
  // 3-6. CSR build (both graphs batched)
  k_hist<<<(E_TOT + 255)/256, 256, 0, stream>>>(dst1, dst2, deg);
  int nb = (NDST_TOT + 1023)/1024;   // 118
  k_scan_sum<<<nb, 256, 0, stream>>>(deg, bs, NDST_TOT);
  k_scan_bsum<<<1, 256, 0, stream>>>(bs, bo, nb);
  k_scan_final<<<nb, 256, 0, stream>>>(deg, bo, offs, cur, NDST_TOT);
  // 7. scatter both graphs
  k_scatter<<<(E_TOT + 255)/256, 256, 0, stream>>>(src1, dst1, ety1, norm1, comp1,
                                                   src2, dst2, ety2, norm2, comp2,
                                                   cur, ssrc, sc);
  // 8. layer 1 fused agg+gemm (+relu)
  k_agg_gemm1<<<N_DST1/16, 256, 0, stream>>>(x_bf, offs, ssrc, sc, Btab1, b1, h_bf);
  // 9. layer 2 fused agg+gemm -> out
  k_agg_gemm2<<<N_DST2/16, 256, 0, stream>>>(h_bf, offs + N_DST1, ssrc, sc, Btab2, b2, out);

  (void)in_sizes; (void)n_in; (void)out_size; (void)ws_size;
}

// Round 3
// 495.122 us; speedup vs baseline: 1.2045x; 1.0939x over previous
//
#include <hip/hip_runtime.h>
#include <stdint.h>

#define NUM_NODES 1000000
#define H_DIM 64
#define OUT_DIM 32
#define NUM_RELS 64
#define NUM_BASES 4
#define N_SRC0 400000
#define N_DST1 100000
#define N_DST2 20000
#define E1 600000
#define E2 300000
#define NDST_TOT (N_DST1 + N_DST2)
#define E_TOT (E1 + E2)

typedef __attribute__((ext_vector_type(8))) short bf16x8;
typedef __attribute__((ext_vector_type(4))) float floatx4;

__device__ __forceinline__ unsigned short f2bf(float f){
  union{float f; unsigned u;} v; v.f=f;
  unsigned u=v.u;
  unsigned r=(u + 0x7FFFu + ((u>>16)&1u))>>16;
  return (unsigned short)r;
}
__device__ __forceinline__ float bf2f(unsigned short h){
  union{unsigned u; float f;} v; v.u=((unsigned)h)<<16; return v.f;
}

// ---- init: zero deg[120000] + build B fragment tables ----
__global__ void k_init(const float* __restrict__ V1, const float* __restrict__ V2,
                       ushort* __restrict__ Btab1, ushort* __restrict__ Btab2,
                       int* __restrict__ deg){
  int t = blockIdx.x*blockDim.x + threadIdx.x;
  if (t < NDST_TOT) deg[t] = 0;
  if (t < 16384){
    int j = t & 7, lane = (t>>3)&63, kk = (t>>9)&7, nt = t>>12;     // nt<4
    int kdim = kk*32 + (lane>>4)*8 + j;
    int o = nt*16 + (lane&15);
    int k = kdim>>2, b = kdim&3;
    Btab1[t] = f2bf(V1[(b*64 + k)*64 + o]);
  } else if (t < 24576){
    int u = t - 16384;
    int j = u & 7, lane = (u>>3)&63, kk = (u>>9)&7, nt = u>>12;     // nt<2
    int kdim = kk*32 + (lane>>4)*8 + j;
    int o = nt*16 + (lane&15);
    int k = kdim>>2, b = kdim&3;
    Btab2[u] = f2bf(V2[(b*64 + k)*32 + o]);
  }
}

// ---- histogram over both graphs' dst (graph2 offset by N_DST1) ----
__global__ void k_hist(const int* __restrict__ dst1, const int* __restrict__ dst2,
                       int* __restrict__ deg){
  int t = blockIdx.x*blockDim.x + threadIdx.x;
  if (t < E1) atomicAdd(&deg[dst1[t]], 1);
  else if (t < E_TOT) atomicAdd(&deg[N_DST1 + dst2[t - E1]], 1);
}

// ---- 3-kernel exclusive scan over deg[NDST_TOT] ----
__global__ void k_scan_sum(const int* __restrict__ deg, int* __restrict__ bsum, int n){
  __shared__ int lds[256];
  int tid = threadIdx.x;
  int base = blockIdx.x*1024 + tid*4;
  int s = 0;
  #pragma unroll
  for (int j=0;j<4;j++){ int i = base+j; if (i<n) s += deg[i]; }
  lds[tid] = s; __syncthreads();
  for (int off=128; off>0; off>>=1){ if (tid<off) lds[tid] += lds[tid+off]; __syncthreads(); }
  if (tid==0) bsum[blockIdx.x] = lds[0];
}

__global__ void k_scan_bsum(const int* __restrict__ bsum, int* __restrict__ boff, int nb){
  __shared__ int lds[256];
  int tid = threadIdx.x;
  int v = (tid<nb) ? bsum[tid] : 0;
  lds[tid] = v; __syncthreads();
  for (int off=1; off<256; off<<=1){
    int t = (tid>=off) ? lds[tid-off] : 0; __syncthreads();
    lds[tid] += t; __syncthreads();
  }
  if (tid<nb) boff[tid] = lds[tid] - v;   // exclusive
}

__global__ void k_scan_final(const int* __restrict__ deg, const int* __restrict__ boff,
                             int* __restrict__ offs, int* __restrict__ cursor, int n){
  __shared__ int lds[256];
  int tid = threadIdx.x;
  int base = blockIdx.x*1024 + tid*4;
  int a[4]; int s = 0;
  #pragma unroll
  for (int j=0;j<4;j++){ int i = base+j; a[j] = (i<n)?deg[i]:0; s += a[j]; }
  lds[tid] = s; __syncthreads();
  for (int off=1; off<256; off<<=1){
    int t = (tid>=off) ? lds[tid-off] : 0; __syncthreads();
    lds[tid] += t; __syncthreads();
  }
  int run = boff[blockIdx.x] + (lds[tid] - s);   // global exclusive prefix
  #pragma unroll
  for (int j=0;j<4;j++){
    int i = base+j;
    if (i<n){
      offs[i] = run; cursor[i] = run;
      run += a[j];
      if (i == n-1) offs[n] = run;
    }
  }
}

// ---- scatter both graphs into dst-sorted edge arrays ----
// Layer-1 edges store the RESOLVED emb row (input_nodes[src1[e]]) so agg1
// reads emb directly (no x staging).
__global__ void k_scatter(const int* __restrict__ input_nodes,
                          const int* __restrict__ src1, const int* __restrict__ dst1,
                          const int* __restrict__ ety1, const float* __restrict__ nrm1,
                          const float* __restrict__ comp1,
                          const int* __restrict__ src2, const int* __restrict__ dst2,
                          const int* __restrict__ ety2, const float* __restrict__ nrm2,
                          const float* __restrict__ comp2,
                          int* __restrict__ cursor, int* __restrict__ ssrc,
                          float4* __restrict__ sc){
  int t = blockIdx.x*blockDim.x + threadIdx.x;
  int d, s, et; float nv; const float* comp;
  if (t < E1){
    d = dst1[t]; s = input_nodes[src1[t]]; et = ety1[t]; nv = nrm1[t]; comp = comp1;
  } else if (t < E_TOT){
    int e = t - E1;
    d = N_DST1 + dst2[e]; s = src2[e]; et = ety2[e]; nv = nrm2[e]; comp = comp2;
  } else return;
  int p = atomicAdd(&cursor[d], 1);
  ssrc[p] = s;
  float4 cp = ((const float4*)comp)[et];
  float4 c; c.x = cp.x*nv; c.y = cp.y*nv; c.z = cp.z*nv; c.w = cp.w*nv;
  sc[p] = c;
}

// ---- fused aggregate + GEMM per layer ----
// Block = 256 threads = 4 waves, 16 dst rows. Wave w aggregates rows
// w*4..w*4+3 into registers (fp32), stages 16x256 bf16 tile in padded LDS
// (stride 264 -> only 2-way bank aliasing, free), then computes one MFMA
// n-tile. Edge meta batched via lane-parallel load + shfl broadcast; edge
// loop unrolled x2 so two source-row loads are in flight.

__global__ __launch_bounds__(256) void k_agg_gemm1(
    const float* __restrict__ emb, const int* __restrict__ offs,
    const int* __restrict__ ssrc, const float4* __restrict__ sc,
    const ushort* __restrict__ Btab, const float* __restrict__ bias,
    ushort* __restrict__ h_bf){
  __shared__ ushort zt[16][264];
  int lane = threadIdx.x & 63;
  int w = threadIdx.x >> 6;
  int mbase = blockIdx.x * 16;
  for (int j = 0; j < 4; j++){
    int row = w*4 + j;
    int d = mbase + row;
    int e0 = offs[d], e1 = offs[d+1];
    float a0=0.f, a1=0.f, a2=0.f, a3=0.f;
    for (int base = e0; base < e1; base += 64){
      int m = e1 - base; if (m > 64) m = 64;
      int se = 0; float4 ce = {0.f,0.f,0.f,0.f};
      if (lane < m){ se = ssrc[base + lane]; ce = sc[base + lane]; }
      int i = 0;
      for (; i + 1 < m; i += 2){
        int s0 = __shfl(se, i), s1 = __shfl(se, i+1);
        float xv0 = emb[(size_t)s0*64 + lane];
        float xv1 = emb[(size_t)s1*64 + lane];
        float c0x=__shfl(ce.x,i), c0y=__shfl(ce.y,i), c0z=__shfl(ce.z,i), c0w=__shfl(ce.w,i);
        float c1x=__shfl(ce.x,i+1), c1y=__shfl(ce.y,i+1), c1z=__shfl(ce.z,i+1), c1w=__shfl(ce.w,i+1);
        a0 = fmaf(c0x, xv0, a0); a1 = fmaf(c0y, xv0, a1);
        a2 = fmaf(c0z, xv0, a2); a3 = fmaf(c0w, xv0, a3);
        a0 = fmaf(c1x, xv1, a0); a1 = fmaf(c1y, xv1, a1);
        a2 = fmaf(c1z, xv1, a2); a3 = fmaf(c1w, xv1, a3);
      }
      if (i < m){
        int s0 = __shfl(se, i);
        float xv0 = emb[(size_t)s0*64 + lane];
        float c0x=__shfl(ce.x,i), c0y=__shfl(ce.y,i), c0z=__shfl(ce.z,i), c0w=__shfl(ce.w,i);
        a0 = fmaf(c0x, xv0, a0); a1 = fmaf(c0y, xv0, a1);
        a2 = fmaf(c0z, xv0, a2); a3 = fmaf(c0w, xv0, a3);
      }
    }
    ushort4 o; o.x=f2bf(a0); o.y=f2bf(a1); o.z=f2bf(a2); o.w=f2bf(a3);
    *(ushort4*)&zt[row][lane*4] = o;
  }
  __syncthreads();
  int quad = lane>>4, l15 = lane&15;
  bf16x8 a[8];
  #pragma unroll
  for (int kk=0; kk<8; kk++)
    a[kk] = *(const bf16x8*)&zt[l15][kk*32 + quad*8];
  floatx4 acc = {0.f,0.f,0.f,0.f};
  #pragma unroll
  for (int kk=0; kk<8; kk++){
    bf16x8 b = *((const bf16x8*)(Btab + ((w*8 + kk)*64 + lane)*8));
    acc = __builtin_amdgcn_mfma_f32_16x16x32_bf16(a[kk], b, acc, 0, 0, 0);
  }
  int col = w*16 + l15;
  float bv = bias[col];
  #pragma unroll
  for (int r=0; r<4; r++){
    int row = mbase + quad*4 + r;
    float v = fmaxf(acc[r] + bv, 0.f);
    h_bf[(size_t)row*64 + col] = f2bf(v);
  }
}

__global__ __launch_bounds__(256) void k_agg_gemm2(
    const ushort* __restrict__ hin, const int* __restrict__ offs,
    const int* __restrict__ ssrc, const float4* __restrict__ sc,
    const ushort* __restrict__ Btab, const float* __restrict__ bias,
    float* __restrict__ out){
  __shared__ ushort zt[16][264];
  int lane = threadIdx.x & 63;
  int w = threadIdx.x >> 6;
  int mbase = blockIdx.x * 16;
  for (int j = 0; j < 4; j++){
    int row = w*4 + j;
    int d = mbase + row;
    int e0 = offs[d], e1 = offs[d+1];
    float a0=0.f, a1=0.f, a2=0.f, a3=0.f;
    for (int base = e0; base < e1; base += 64){
      int m = e1 - base; if (m > 64) m = 64;
      int se = 0; float4 ce = {0.f,0.f,0.f,0.f};
      if (lane < m){ se = ssrc[base + lane]; ce = sc[base + lane]; }
      int i = 0;
      for (; i + 1 < m; i += 2){
        int s0 = __shfl(se, i), s1 = __shfl(se, i+1);
        float xv0 = bf2f(hin[(size_t)s0*64 + lane]);
        float xv1 = bf2f(hin[(size_t)s1*64 + lane]);
        float c0x=__shfl(ce.x,i), c0y=__shfl(ce.y,i), c0z=__shfl(ce.z,i), c0w=__shfl(ce.w,i);
        float c1x=__shfl(ce.x,i+1), c1y=__shfl(ce.y,i+1), c1z=__shfl(ce.z,i+1), c1w=__shfl(ce.w,i+1);
        a0 = fmaf(c0x, xv0, a0); a1 = fmaf(c0y, xv0, a1);
        a2 = fmaf(c0z, xv0, a2); a3 = fmaf(c0w, xv0, a3);
        a0 = fmaf(c1x, xv1, a0); a1 = fmaf(c1y, xv1, a1);
        a2 = fmaf(c1z, xv1, a2); a3 = fmaf(c1w, xv1, a3);
      }
      if (i < m){
        int s0 = __shfl(se, i);
        float xv0 = bf2f(hin[(size_t)s0*64 + lane]);
        float c0x=__shfl(ce.x,i), c0y=__shfl(ce.y,i), c0z=__shfl(ce.z,i), c0w=__shfl(ce.w,i);
        a0 = fmaf(c0x, xv0, a0); a1 = fmaf(c0y, xv0, a1);
        a2 = fmaf(c0z, xv0, a2); a3 = fmaf(c0w, xv0, a3);
      }
    }
    ushort4 o; o.x=f2bf(a0); o.y=f2bf(a1); o.z=f2bf(a2); o.w=f2bf(a3);
    *(ushort4*)&zt[row][lane*4] = o;
  }
  __syncthreads();
  if (w >= 2) return;                      // N=32 -> 2 n-tiles
  int quad = lane>>4, l15 = lane&15;
  bf16x8 a[8];
  #pragma unroll
  for (int kk=0; kk<8; kk++)
    a[kk] = *(const bf16x8*)&zt[l15][kk*32 + quad*8];
  floatx4 acc = {0.f,0.f,0.f,0.f};
  #pragma unroll
  for (int kk=0; kk<8; kk++){
    bf16x8 b = *((const bf16x8*)(Btab + ((w*8 + kk)*64 + lane)*8));
    acc = __builtin_amdgcn_mfma_f32_16x16x32_bf16(a[kk], b, acc, 0, 0, 0);
  }
  int col = w*16 + l15;
  float bv = bias[col];
  #pragma unroll
  for (int r=0; r<4; r++){
    int row = mbase + quad*4 + r;
    out[(size_t)row*32 + col] = acc[r] + bv;
  }
}

extern "C" void kernel_launch(void* const* d_in, const int* in_sizes, int n_in,
                              void* d_out, int out_size, void* d_ws, size_t ws_size,
                              hipStream_t stream){
  const int*   input_nodes = (const int*)  d_in[0];
  const int*   src1  = (const int*)  d_in[1];
  const int*   dst1  = (const int*)  d_in[2];
  const int*   ety1  = (const int*)  d_in[3];
  const float* norm1 = (const float*)d_in[4];
  const int*   src2  = (const int*)  d_in[5];
  const int*   dst2  = (const int*)  d_in[6];
  const int*   ety2  = (const int*)  d_in[7];
  const float* norm2 = (const float*)d_in[8];
  const float* emb   = (const float*)d_in[9];
  const float* V1    = (const float*)d_in[10];
  const float* comp1 = (const float*)d_in[11];
  const float* b1    = (const float*)d_in[12];
  const float* V2    = (const float*)d_in[13];
  const float* comp2 = (const float*)d_in[14];
  const float* b2    = (const float*)d_in[15];
  float* out = (float*)d_out;

  char* p = (char*)d_ws;
  auto alloc = [&](size_t bytes)->char*{
    char* r = p; p += (bytes + 255) & ~(size_t)255; return r;
  };
  ushort* h_bf  = (ushort*)alloc((size_t)N_DST1*64*2);     // 12.8 MB
  ushort* Btab1 = (ushort*)alloc(16384*2);
  ushort* Btab2 = (ushort*)alloc(8192*2);
  int* deg  = (int*)alloc((size_t)NDST_TOT*4);
  int* cur  = (int*)alloc((size_t)NDST_TOT*4);
  int* offs = (int*)alloc((size_t)(NDST_TOT+1)*4);
  int* bs   = (int*)alloc(256*4);
  int* bo   = (int*)alloc(256*4);
  int* ssrc = (int*)alloc((size_t)E_TOT*4);
  float4* sc = (float4*)alloc((size_t)E_TOT*16);

  // 1. init (deg zero + B tables)
  k_init<<<(NDST_TOT + 255)/256, 256, 0, stream>>>(V1, V2, Btab1, Btab2, deg);
  // 2-5. CSR build (both graphs batched)
  k_hist<<<(E_TOT + 255)/256, 256, 0, stream>>>(dst1, dst2, deg);
  int nb = (NDST_TOT + 1023)/1024;   // 118
  k_scan_sum<<<nb, 256, 0, stream>>>(deg, bs, NDST_TOT);
  k_scan_bsum<<<1, 256, 0, stream>>>(bs, bo, nb);
  k_scan_final<<<nb, 256, 0, stream>>>(deg, bo, offs, cur, NDST_TOT);
  // 6. scatter both graphs (resolves input_nodes for layer 1)
  k_scatter<<<(E_TOT + 255)/256, 256, 0, stream>>>(input_nodes,
                                                   src1, dst1, ety1, norm1, comp1,
                                                   src2, dst2, ety2, norm2, comp2,
                                                   cur, ssrc, sc);
  // 7. layer 1 fused agg(direct emb)+gemm (+relu)
  k_agg_gemm1<<<N_DST1/16, 256, 0, stream>>>(emb, offs, ssrc, sc, Btab1, b1, h_bf);
  // 8. layer 2 fused agg+gemm -> out
  k_agg_gemm2<<<N_DST2/16, 256, 0, stream>>>(h_bf, offs + N_DST1, ssrc, sc, Btab2, b2, out);

  (void)in_sizes; (void)n_in; (void)out_size; (void)ws_size;
}